// Round 2
// baseline (718.493 us; speedup 1.0000x reference)
//
#include <hip/hip_runtime.h>

// Problem constants (from reference): R=128, T=4096, M=32768, N=4096, L=16384
#define T_DIM 4096
#define R_DIM 128
#define M_DIM 32768
#define N_DIM 4096
#define L_DIM 16384

typedef __attribute__((ext_vector_type(8))) short short8;   // 8 x bf16 (4 VGPRs)
typedef __attribute__((ext_vector_type(4))) float float4_;  // 4 x f32 acc

__device__ __forceinline__ unsigned short f2bf(float f) {
    // round-to-nearest-even fp32 -> bf16 (inputs finite)
    unsigned int u = __float_as_uint(f);
    unsigned int r = (u + 0x7fffu + ((u >> 16) & 1u)) >> 16;
    return (unsigned short)r;
}

// ---------------------------------------------------------------------------
// 1) x_pos = relu(x) -> d_out[0:R*T]; Xt[t][k] = bf16(x_pos[k][t]) (transposed
//    so MFMA B-operand loads are contiguous 16B)
__global__ __launch_bounds__(256) void prep_x(const float* __restrict__ x,
                                              float* __restrict__ xpos,
                                              unsigned short* __restrict__ Xt) {
    int id = blockIdx.x * 256 + threadIdx.x;     // < 524288
    int k = id >> 12;                            // row in [0,128)
    int t = id & (T_DIM - 1);
    float v = fmaxf(x[id], 0.0f);
    xpos[id] = v;
    Xt[t * R_DIM + k] = f2bf(v);
}

// ---------------------------------------------------------------------------
// 2) Ab = bf16(A); B_seg[node_ids[m]][k] += A[m][k]  (segment-sum of A rows)
__global__ __launch_bounds__(256) void cast_A_seg(const float* __restrict__ A,
                                                  const int* __restrict__ node_ids,
                                                  unsigned short* __restrict__ Ab,
                                                  float* __restrict__ Bseg) {
    int id = blockIdx.x * 256 + threadIdx.x;     // < 4194304
    int m = id >> 7;
    int k = id & (R_DIM - 1);
    float v = A[id];
    Ab[id] = f2bf(v);
    atomicAdd(Bseg + node_ids[m] * R_DIM + k, v);
}

// ---------------------------------------------------------------------------
// 3) Bb = bf16(B_seg)
__global__ __launch_bounds__(256) void cast_Bseg(const float* __restrict__ Bseg,
                                                 unsigned short* __restrict__ Bb) {
    int id = blockIdx.x * 256 + threadIdx.x;     // < 524288
    Bb[id] = f2bf(Bseg[id]);
}

// ---------------------------------------------------------------------------
// 4) w[l] = t0*alpha*radio; rcap[l] = 1/cap; cterm += t0*radio (wave-reduced)
__global__ __launch_bounds__(256) void prep_lw(const float* __restrict__ t0,
                                               const float* __restrict__ cap,
                                               const float* __restrict__ radio,
                                               const float* __restrict__ alpha_raw,
                                               float* __restrict__ w,
                                               float* __restrict__ rcap,
                                               float* __restrict__ cterm) {
    int l = blockIdx.x * 256 + threadIdx.x;      // < 16384
    float alpha = 0.01f + 0.99f / (1.0f + expf(-alpha_raw[0]));
    float tv = t0[l], rv = radio[l];
    w[l] = tv * alpha * rv;
    rcap[l] = 1.0f / cap[l];
    float p = tv * rv;
    #pragma unroll
    for (int off = 32; off > 0; off >>= 1) p += __shfl_down(p, off, 64);
    if ((threadIdx.x & 63) == 0) atomicAdd(cterm, p);
}

// ---------------------------------------------------------------------------
// 5) C[M x T] = Arows[M x 128](bf16) @ Xt^T  (Xt stored [T x 128] k-contig)
//    grid = (T/128, Mrows/128); block = 256 (4 waves, 2x2), wave tile 64x64.
//    LDS-free: both operands are 16B contiguous dwordx4 loads, L2-cached.
__global__ __launch_bounds__(256) void gemm_mfma(const unsigned short* __restrict__ Am,
                                                 const unsigned short* __restrict__ Xt,
                                                 float* __restrict__ C) {
    const int lane = threadIdx.x & 63;
    const int wid  = threadIdx.x >> 6;
    const int quad = lane >> 4;
    const int l16  = lane & 15;
    const int mBase = blockIdx.y * 128 + (wid & 1) * 64;
    const int tBase = blockIdx.x * 128 + (wid >> 1) * 64;

    float4_ acc[4][4];
    #pragma unroll
    for (int i = 0; i < 4; i++)
        #pragma unroll
        for (int j = 0; j < 4; j++)
            acc[i][j] = (float4_)(0.0f);

    #pragma unroll
    for (int ks = 0; ks < 4; ks++) {
        const int k0 = ks * 32 + quad * 8;
        short8 a[4], b[4];
        #pragma unroll
        for (int i = 0; i < 4; i++) {
            size_t m = (size_t)(mBase + i * 16 + l16);
            a[i] = *(const short8*)(Am + m * R_DIM + k0);
        }
        #pragma unroll
        for (int j = 0; j < 4; j++) {
            size_t t = (size_t)(tBase + j * 16 + l16);
            b[j] = *(const short8*)(Xt + t * R_DIM + k0);
        }
        #pragma unroll
        for (int i = 0; i < 4; i++)
            #pragma unroll
            for (int j = 0; j < 4; j++)
                acc[i][j] = __builtin_amdgcn_mfma_f32_16x16x32_bf16(a[i], b[j], acc[i][j], 0, 0, 0);
    }

    // C/D layout: row = quad*4 + reg, col = l16 (verified m89/m91)
    #pragma unroll
    for (int i = 0; i < 4; i++) {
        int row0 = mBase + i * 16 + quad * 4;
        #pragma unroll
        for (int j = 0; j < 4; j++) {
            int col = tBase + j * 16 + l16;
            #pragma unroll
            for (int r = 0; r < 4; r++) {
                C[(size_t)(row0 + r) * T_DIM + col] = acc[i][j][r];
            }
        }
    }
}

// ---------------------------------------------------------------------------
// 6) y[t] (+=) sum_l w[l] * max(nflow[row_node[l]][t]*rcap[l], 1e-6)^beta
//    grid = (T/256, 32 L-chunks); chunk 0 also adds the constant term.
__global__ __launch_bounds__(256) void stage5(const float* __restrict__ nflow,
                                              const int* __restrict__ row_node,
                                              const float* __restrict__ w,
                                              const float* __restrict__ rcap,
                                              const float* __restrict__ beta_raw,
                                              const float* __restrict__ cterm,
                                              float* __restrict__ y) {
    const int t  = blockIdx.x * 256 + threadIdx.x;
    const int lc = blockIdx.y;
    const int LPC = L_DIM / 32;                  // 512
    const int l0 = lc * LPC;
    float beta = 1.0f + 7.0f / (1.0f + expf(-beta_raw[0]));
    float acc = 0.0f;
    for (int i = 0; i < LPC; i++) {
        int l = l0 + i;
        int rn = row_node[l];
        float flow = nflow[(size_t)rn * T_DIM + t];
        float ratio = fmaxf(flow * rcap[l], 1e-6f);
        // ratio^beta = 2^(beta * log2(ratio)); v_log_f32/v_exp_f32 are log2/exp2
        acc += w[l] * __builtin_amdgcn_exp2f(beta * __builtin_amdgcn_logf(ratio));
    }
    if (lc == 0) acc += cterm[0];
    atomicAdd(&y[t], acc);
}

// ---------------------------------------------------------------------------
extern "C" void kernel_launch(void* const* d_in, const int* in_sizes, int n_in,
                              void* d_out, int out_size, void* d_ws, size_t ws_size,
                              hipStream_t stream) {
    const float* x         = (const float*)d_in[0];
    const float* A         = (const float*)d_in[1];
    const float* t0        = (const float*)d_in[2];
    const float* cap       = (const float*)d_in[3];
    const float* radio     = (const float*)d_in[4];
    const float* alpha_raw = (const float*)d_in[5];
    const float* beta_raw  = (const float*)d_in[6];
    const int*   node_ids  = (const int*)d_in[7];
    const int*   row_node  = (const int*)d_in[8];

    float* out   = (float*)d_out;
    float* xpos  = out;                                   // R*T   = 524288
    float* cpred = out + (size_t)R_DIM * T_DIM;           // M*T   = 134217728
    float* y     = cpred + (size_t)M_DIM * T_DIM;         // T     = 4096

    char* ws = (char*)d_ws;
    unsigned short* Xt   = (unsigned short*)(ws);                       // 1 MB
    unsigned short* Ab   = (unsigned short*)(ws + (1u << 20));          // 8 MB
    unsigned short* Bb   = (unsigned short*)(ws + (9u << 20));          // 1 MB
    float*          Bseg = (float*)(ws + (10u << 20));                  // 2 MB
    float*          w    = (float*)(ws + (12u << 20));                  // 64 KB
    float*          rcap = (float*)(ws + (12u << 20) + 65536);          // 64 KB
    float*          csum = (float*)(ws + (12u << 20) + 131072);         // 4 B
    float*          nflw = (float*)(ws + (16u << 20));                  // 64 MB

    // zero the atomic-accumulated regions (ws/d_out are poisoned each call)
    (void)hipMemsetAsync(Bseg, 0, (size_t)N_DIM * R_DIM * sizeof(float), stream);
    (void)hipMemsetAsync(csum, 0, sizeof(float), stream);
    (void)hipMemsetAsync(y, 0, T_DIM * sizeof(float), stream);

    prep_x    <<<dim3((R_DIM * T_DIM) / 256), 256, 0, stream>>>(x, xpos, Xt);
    cast_A_seg<<<dim3((M_DIM * R_DIM) / 256), 256, 0, stream>>>(A, node_ids, Ab, Bseg);
    cast_Bseg <<<dim3((N_DIM * R_DIM) / 256), 256, 0, stream>>>(Bseg, Bb);
    prep_lw   <<<dim3(L_DIM / 256), 256, 0, stream>>>(t0, cap, radio, alpha_raw, w, rcap, csum);

    // c_pred = A @ x_pos   [32768 x 4096]
    gemm_mfma<<<dim3(T_DIM / 128, M_DIM / 128), 256, 0, stream>>>(Ab, Xt, cpred);
    // node_flow = B_seg @ x_pos   [4096 x 4096]
    gemm_mfma<<<dim3(T_DIM / 128, N_DIM / 128), 256, 0, stream>>>(Bb, Xt, nflw);

    stage5<<<dim3(T_DIM / 256, 32), 256, 0, stream>>>(nflw, row_node, w, rcap, beta_raw, csum, y);
}